// Round 4
// baseline (65.486 us; speedup 1.0000x reference)
//
#include <hip/hip_runtime.h>
#include <hip/hip_bf16.h>

typedef __attribute__((ext_vector_type(8))) short bf16x8;
typedef __attribute__((ext_vector_type(4))) float f32x4;

#define T_DIM 32
#define B_DIM 8192
#define S_DIM 256
#define H_DIM 128
#define BM    32              // batch rows per chunk
#define NCH   16              // chunks per block (32*16 = 512 rows/block)
#define BLOCKS_PER_T 16
// grid = 32 t * 16 = 512 blocks = 2 per CU

// DMA global->LDS, 16B per lane, LDS dest = wave-uniform base + lane*16 (linear)
#define GLD_LDS16(gsrc, ldst)                                                  \
  __builtin_amdgcn_global_load_lds(                                            \
      (const __attribute__((address_space(1))) void*)(gsrc),                   \
      (__attribute__((address_space(3))) void*)(ldst), 16, 0, 0)

__device__ __forceinline__ uint32_t cvt_pk_bf16(float lo, float hi) {
  uint32_t r;
  asm("v_cvt_pk_bf16_f32 %0, %1, %2" : "=v"(r) : "v"(lo), "v"(hi));
  return r;
}

__global__ __launch_bounds__(256, 2) void cvar_mlp_kernel(
    const float* __restrict__ states, const float* __restrict__ W1,
    const float* __restrict__ b1, const float* __restrict__ W2,
    const float* __restrict__ b2, float* __restrict__ out)
{
  // double-buffered 32x256 f32 states tile; LINEAR layout for DMA,
  // source-preswizzled: LDS granule (row,g) holds global granule g^(row&7)
  __shared__ __align__(16) float ldsA[2][BM * S_DIM];   // 2 x 32 KB
  __shared__ float red[2][4][BM];

  const int tid  = threadIdx.x;
  const int wid  = tid >> 6;
  const int lane = tid & 63;
  const int l15  = lane & 15;
  const int lg   = lane >> 4;          // 0..3

  // XCD-grouped: blocks with same (bidx&7) share a t-range -> W1[t] L2-local
  const int bidx = blockIdx.x;         // 0..511
  const int xcd  = bidx & 7;
  const int slot = bidx >> 3;          // 0..63
  const int t    = xcd * 4 + (slot >> 4);
  const int cg   = slot & 15;
  const int b0   = cg * (BM * NCH);

  const float*  Ag  = states + ((size_t)t * B_DIM + b0) * S_DIM;
  const float4* A4  = reinterpret_cast<const float4*>(Ag);
  const float*  W1g = W1 + (size_t)t * (S_DIM * H_DIM);

  // ---- DMA chunk 0 -> ldsA[0] (HBM latency starts now, no VGPR cost) ----
#pragma unroll
  for (int i = 0; i < 8; ++i) {
    const int rowt = i * 4 + wid;                          // row in tile
    const int sg   = lane ^ (rowt & 7);                    // preswizzled src granule
    GLD_LDS16(A4 + (size_t)0 * 2048 + rowt * 64 + sg,
              &ldsA[0][(i * 256 + wid * 64) * 4]);
  }

  // ---- W1 fragment preload into registers (L2; amortized over 16 chunks) ----
  // B-frag for mfma_f32_16x16x32_bf16: lane holds col n=lane&15, k=ks*32+lg*8+j
  bf16x8 bfr[2][8];
#pragma unroll
  for (int nloc = 0; nloc < 2; ++nloc) {
    const int ncol = (wid * 2 + nloc) * 16 + l15;
#pragma unroll
    for (int ks = 0; ks < 8; ++ks) {
      const int kbase = ks * 32 + lg * 8;
      float e[8];
#pragma unroll
      for (int j = 0; j < 8; ++j)
        e[j] = W1g[(size_t)(kbase + j) * H_DIM + ncol];
      union { uint32_t u[4]; bf16x8 v; } uu;
      uu.u[0] = cvt_pk_bf16(e[0], e[1]);
      uu.u[1] = cvt_pk_bf16(e[2], e[3]);
      uu.u[2] = cvt_pk_bf16(e[4], e[5]);
      uu.u[3] = cvt_pk_bf16(e[6], e[7]);
      bfr[nloc][ks] = uu.v;
    }
  }

  float b1c[2], w2c[2];
#pragma unroll
  for (int nloc = 0; nloc < 2; ++nloc) {
    const int col = (wid * 2 + nloc) * 16 + l15;
    b1c[nloc] = b1[(size_t)t * H_DIM + col];
    w2c[nloc] = W2[(size_t)t * H_DIM + col];
  }
  const float b2t = b2[t];
  float* outt = out + (size_t)t * B_DIM + b0;

  __syncthreads();   // drains vmcnt -> chunk 0 resident

  // ---- pipelined chunk loop: issue DMA(c+1) -> compute(c) -> barrier ----
  for (int c = 0; c < NCH; ++c) {
    const int cur = c & 1;

    // async DMA next chunk into the other buffer (safe: its readers passed
    // the barrier at end of iteration c-1)
    if (c + 1 < NCH) {
#pragma unroll
      for (int i = 0; i < 8; ++i) {
        const int rowt = i * 4 + wid;
        const int sg   = lane ^ (rowt & 7);
        GLD_LDS16(A4 + (size_t)(c + 1) * 2048 + rowt * 64 + sg,
                  &ldsA[cur ^ 1][(i * 256 + wid * 64) * 4]);
      }
    }

    // MFMA: 32 rows x this wave's 32 cols; A-frags read f32 (deswizzle XOR) + cvt
    f32x4 acc[2][2];
#pragma unroll
    for (int mt = 0; mt < 2; ++mt)
#pragma unroll
      for (int nloc = 0; nloc < 2; ++nloc)
        acc[mt][nloc] = (f32x4){0.f, 0.f, 0.f, 0.f};

#pragma unroll
    for (int mt = 0; mt < 2; ++mt) {
      const int r = mt * 16 + l15;
      const int m = r & 7;
      bf16x8 afr[8];
#pragma unroll
      for (int ks = 0; ks < 8; ++ks) {
        const int ga = ks * 8 + lg * 2;   // granule pair for k = ks*32+lg*8 ..+7
        const float4 f0 = *reinterpret_cast<const float4*>(
            &ldsA[cur][r * S_DIM + ((ga    ) ^ m) * 4]);
        const float4 f1 = *reinterpret_cast<const float4*>(
            &ldsA[cur][r * S_DIM + ((ga + 1) ^ m) * 4]);
        union { uint32_t u[4]; bf16x8 v; } uu;
        uu.u[0] = cvt_pk_bf16(f0.x, f0.y);
        uu.u[1] = cvt_pk_bf16(f0.z, f0.w);
        uu.u[2] = cvt_pk_bf16(f1.x, f1.y);
        uu.u[3] = cvt_pk_bf16(f1.z, f1.w);
        afr[ks] = uu.v;
      }
#pragma unroll
      for (int ks = 0; ks < 8; ++ks) {
        acc[mt][0] = __builtin_amdgcn_mfma_f32_16x16x32_bf16(afr[ks], bfr[0][ks], acc[mt][0], 0, 0, 0);
        acc[mt][1] = __builtin_amdgcn_mfma_f32_16x16x32_bf16(afr[ks], bfr[1][ks], acc[mt][1], 0, 0, 0);
      }
    }

    // fused epilogue: +b1, SiLU, *W2, 16-lane row-reduce -> red[cur]
#pragma unroll
    for (int mt = 0; mt < 2; ++mt) {
      float part[4];
#pragma unroll
      for (int r = 0; r < 4; ++r) {
        float s = 0.f;
#pragma unroll
        for (int nloc = 0; nloc < 2; ++nloc) {
          const float h   = acc[mt][nloc][r] + b1c[nloc];
          const float sig = 1.f / (1.f + __expf(-h));
          s += h * sig * w2c[nloc];
        }
        s += __shfl_xor(s, 1);
        s += __shfl_xor(s, 2);
        s += __shfl_xor(s, 4);
        s += __shfl_xor(s, 8);
        part[r] = s;
      }
      if (l15 == 0) {
#pragma unroll
        for (int r = 0; r < 4; ++r)
          red[cur][wid][mt * 16 + lg * 4 + r] = part[r];
      }
    }

    // one barrier per iteration: drains DMA (vmcnt) + publishes red[cur]
    __syncthreads();

    if (tid < BM) {
      const float o = red[cur][0][tid] + red[cur][1][tid] +
                      red[cur][2][tid] + red[cur][3][tid] + b2t;
      outt[c * BM + tid] = o;
    }
  }
}

extern "C" void kernel_launch(void* const* d_in, const int* in_sizes, int n_in,
                              void* d_out, int out_size, void* d_ws, size_t ws_size,
                              hipStream_t stream) {
  const float* states = (const float*)d_in[0];
  const float* W1     = (const float*)d_in[1];
  const float* b1     = (const float*)d_in[2];
  const float* W2     = (const float*)d_in[3];
  const float* b2     = (const float*)d_in[4];
  float* out          = (float*)d_out;

  const int grid = T_DIM * BLOCKS_PER_T;   // 512
  cvar_mlp_kernel<<<grid, 256, 0, stream>>>(states, W1, b1, W2, b2, out);
}

// Round 5
// 57.931 us; speedup vs baseline: 1.1304x; 1.1304x over previous
//
#include <hip/hip_runtime.h>
#include <hip/hip_bf16.h>

typedef __attribute__((ext_vector_type(8))) short bf16x8;
typedef __attribute__((ext_vector_type(4))) float f32x4;

#define T_DIM 32
#define B_DIM 8192
#define S_DIM 256
#define H_DIM 128
#define NCH   8               // chunks per wave; 16 rows each -> 128 rows/wave
#define BLOCKS_PER_T 16       // block = 4 waves * 128 rows = 512 rows
// grid = 32 t * 16 = 512 blocks = 2/CU, 8 free-running waves/CU

__device__ __forceinline__ uint32_t cvt_pk_bf16(float lo, float hi) {
  uint32_t r;
  asm("v_cvt_pk_bf16_f32 %0, %1, %2" : "=v"(r) : "v"(lo), "v"(hi));
  return r;
}

// issue chunk (c)'s 16 dwordx4 loads for this wave's 16-row strip
#define ISSUE(av, c)                                                           \
  _Pragma("unroll")                                                            \
  for (int ks = 0; ks < 8; ++ks) {                                             \
    av[ks * 2]     = A4[(c) * 1024 + l15 * 64 + ks * 8 + lg * 2];              \
    av[ks * 2 + 1] = A4[(c) * 1024 + l15 * 64 + ks * 8 + lg * 2 + 1];          \
  }

// consume chunk (c): cvt->MFMA vs LDS-resident W1 frags, fused SiLU epilogue
#define COMPUTE(av, c)                                                         \
  {                                                                            \
    f32x4 acc[8];                                                              \
    _Pragma("unroll")                                                          \
    for (int nt = 0; nt < 8; ++nt) acc[nt] = (f32x4){0.f, 0.f, 0.f, 0.f};      \
    _Pragma("unroll")                                                          \
    for (int ks = 0; ks < 8; ++ks) {                                           \
      union { uint32_t u[4]; bf16x8 v; } uu;                                   \
      uu.u[0] = cvt_pk_bf16(av[ks * 2].x,     av[ks * 2].y);                   \
      uu.u[1] = cvt_pk_bf16(av[ks * 2].z,     av[ks * 2].w);                   \
      uu.u[2] = cvt_pk_bf16(av[ks * 2 + 1].x, av[ks * 2 + 1].y);               \
      uu.u[3] = cvt_pk_bf16(av[ks * 2 + 1].z, av[ks * 2 + 1].w);               \
      _Pragma("unroll")                                                        \
      for (int nt = 0; nt < 8; ++nt) {                                         \
        const bf16x8 bq = *reinterpret_cast<const bf16x8*>(                    \
            &ldsW[((nt * 8 + ks) * 64 + lane) * 16]);                          \
        acc[nt] = __builtin_amdgcn_mfma_f32_16x16x32_bf16(uu.v, bq,            \
                                                          acc[nt], 0, 0, 0);  \
      }                                                                        \
    }                                                                          \
    float part[4];                                                             \
    _Pragma("unroll")                                                          \
    for (int r = 0; r < 4; ++r) {                                              \
      float s = 0.f;                                                           \
      _Pragma("unroll")                                                        \
      for (int nt = 0; nt < 8; ++nt) {                                         \
        const float h   = acc[nt][r] + b1c[nt];                                \
        const float sig = 1.f / (1.f + __expf(-h));                            \
        s += h * sig * w2c[nt];                                                \
      }                                                                        \
      s += __shfl_xor(s, 1);                                                   \
      s += __shfl_xor(s, 2);                                                   \
      s += __shfl_xor(s, 4);                                                   \
      s += __shfl_xor(s, 8);                                                   \
      part[r] = s;                                                             \
    }                                                                          \
    if (l15 == 0) {                                                            \
      f32x4 o = {part[0] + b2t, part[1] + b2t, part[2] + b2t, part[3] + b2t};  \
      *reinterpret_cast<f32x4*>(&outw[(c) * 16 + lg * 4]) = o;                 \
    }                                                                          \
  }

__global__ __launch_bounds__(256, 2) void cvar_mlp_kernel(
    const float* __restrict__ states, const float* __restrict__ W1,
    const float* __restrict__ b1, const float* __restrict__ W2,
    const float* __restrict__ b2, float* __restrict__ out)
{
  // W1[t] as bf16 B-fragments, laid out [ntile][ks][lane]*16B (lane-linear
  // ds_read_b128, conflict-free). Static after init -> NO main-loop barriers.
  __shared__ __align__(16) char ldsW[64 * 1024];

  const int tid  = threadIdx.x;
  const int wid  = tid >> 6;
  const int lane = tid & 63;
  const int l15  = lane & 15;
  const int lg   = lane >> 4;          // 0..3

  // XCD-grouped t mapping: same-t blocks share an XCD -> W1[t] L2-local
  const int bidx = blockIdx.x;         // 0..511
  const int xcd  = bidx & 7;
  const int slot = bidx >> 3;          // 0..63
  const int t    = xcd * 4 + (slot >> 4);
  const int cg   = slot & 15;

  // this wave's private 128-row slab
  const float*  Aw = states + ((size_t)t * B_DIM + cg * 512 + wid * 128) * S_DIM;
  const float4* A4 = reinterpret_cast<const float4*>(Aw);
  float*       outw = out + (size_t)t * B_DIM + cg * 512 + wid * 128;

  // ---- issue chunk-0 loads first (deepest latency) ----
  float4 avA[16], avB[16];
  ISSUE(avA, 0);

  // ---- W1 -> LDS bf16 fragments (L2-served gather; once per block) ----
  const float* W1g = W1 + (size_t)t * (S_DIM * H_DIM);
#pragma unroll
  for (int p = 0; p < 2; ++p) {
    const int nt   = wid * 2 + p;
    const int ncol = nt * 16 + l15;
#pragma unroll
    for (int ks = 0; ks < 8; ++ks) {
      const int kbase = ks * 32 + lg * 8;
      float e[8];
#pragma unroll
      for (int j = 0; j < 8; ++j)
        e[j] = W1g[(size_t)(kbase + j) * H_DIM + ncol];
      union { uint32_t u[4]; bf16x8 v; } uu;
      uu.u[0] = cvt_pk_bf16(e[0], e[1]);
      uu.u[1] = cvt_pk_bf16(e[2], e[3]);
      uu.u[2] = cvt_pk_bf16(e[4], e[5]);
      uu.u[3] = cvt_pk_bf16(e[6], e[7]);
      *reinterpret_cast<bf16x8*>(&ldsW[((nt * 8 + ks) * 64 + lane) * 16]) = uu.v;
    }
  }

  float b1c[8], w2c[8];
#pragma unroll
  for (int nt = 0; nt < 8; ++nt) {
    const int col = nt * 16 + l15;
    b1c[nt] = b1[(size_t)t * H_DIM + col];
    w2c[nt] = W2[(size_t)t * H_DIM + col];
  }
  const float b2t = b2[t];

  __syncthreads();   // the ONLY barrier: publishes ldsW

  // ---- barrier-free pipelined stream: waves run fully independently ----
#pragma unroll 1
  for (int c = 0; c < NCH; c += 2) {
    ISSUE(avB, c + 1);
    COMPUTE(avA, c);
    if (c + 2 < NCH) { ISSUE(avA, c + 2); }
    COMPUTE(avB, c + 1);
  }
}

extern "C" void kernel_launch(void* const* d_in, const int* in_sizes, int n_in,
                              void* d_out, int out_size, void* d_ws, size_t ws_size,
                              hipStream_t stream) {
  const float* states = (const float*)d_in[0];
  const float* W1     = (const float*)d_in[1];
  const float* b1     = (const float*)d_in[2];
  const float* W2     = (const float*)d_in[3];
  const float* b2     = (const float*)d_in[4];
  float* out          = (float*)d_out;

  const int grid = T_DIM * BLOCKS_PER_T;   // 512
  cvar_mlp_kernel<<<grid, 256, 0, stream>>>(states, W1, b1, W2, b2, out);
}